// Round 11
// baseline (59.018 us; speedup 1.0000x reference)
//
#include <hip/hip_runtime.h>
#include <hip/hip_bf16.h>

// Problem constants
#define BATCH   4096
#define TWO_B   8192
#define DIM     128
#define INV_TEMP 2.0f      // 1/TEMP, TEMP=0.5
// sqrt(INV_TEMP * log2(e)) folded into the stored bf16 vectors, so the
// similarity accumulator comes out as sim * INV_TEMP * log2(e) and the
// epilogue is a bare exp2.
#define SFOLD 1.6986436f   // sqrt(2.8853900817779268)

typedef __attribute__((ext_vector_type(8))) short bf16x8;   // 8 bf16 = 4 VGPRs
typedef __attribute__((ext_vector_type(4))) float f32x4;

#define NT 64                          // 8192 / 128 tiles per side
#define NPAIRS (NT * (NT + 1) / 2)     // 2080 upper-triangle tile pairs

// Workspace layout (bytes):
//   zb     : __hip_bfloat16[TWO_B*DIM]  [0, 2097152)   pre-scaled by SFOLD
//   rowsum : float[TWO_B]               zeroed by k_normalize
//   ps     : float[1024]                per-block possum partials
#define ZB_BYTES   (TWO_B * DIM * 2)
#define RS_OFFSET  ZB_BYTES
#define PS_OFFSET  (RS_OFFSET + TWO_B * 4)

// async global->LDS, 16B per lane; LDS dest is WAVE-UNIFORM base + lane*16.
__device__ __forceinline__ void gload16(const void* g, void* l) {
    __builtin_amdgcn_global_load_lds(
        (const __attribute__((address_space(1))) unsigned int*)g,
        (__attribute__((address_space(3))) unsigned int*)l, 16, 0, 0);
}

// ---------------------------------------------------------------------------
// Kernel 1: L2-normalize rows of zi AND zj (paired), write bf16 z rows scaled
// by SFOLD, write per-block possum partial, and zero rowsum (8 floats/block).
// ---------------------------------------------------------------------------
__global__ __launch_bounds__(256) void k_normalize(const float* __restrict__ zi,
                                                   const float* __restrict__ zj,
                                                   __hip_bfloat16* __restrict__ zb,
                                                   float* __restrict__ ps,
                                                   float* __restrict__ rowsum) {
    int w = threadIdx.x >> 6;
    int lane = threadIdx.x & 63;
    int r = blockIdx.x * 4 + w;                       // [0, BATCH)

    // zero rowsum: 1024 blocks x 8 floats = 8192
    if (threadIdx.x < 8) rowsum[blockIdx.x * 8 + threadIdx.x] = 0.0f;

    float2 vi = *reinterpret_cast<const float2*>(zi + (size_t)r * DIM + lane * 2);
    float2 vj = *reinterpret_cast<const float2*>(zj + (size_t)r * DIM + lane * 2);
    float ssi = vi.x * vi.x + vi.y * vi.y;
    float ssj = vj.x * vj.x + vj.y * vj.y;
    #pragma unroll
    for (int m = 1; m < 64; m <<= 1) {
        ssi += __shfl_xor(ssi, m, 64);
        ssj += __shfl_xor(ssj, m, 64);
    }
    float invi = 1.0f / fmaxf(sqrtf(ssi), 1e-12f);
    float invj = 1.0f / fmaxf(sqrtf(ssj), 1e-12f);

    float nix = vi.x * invi, niy = vi.y * invi;
    float njx = vj.x * invj, njy = vj.y * invj;

    __hip_bfloat162 hi2, hj2;
    hi2.x = __float2bfloat16(nix * SFOLD);
    hi2.y = __float2bfloat16(niy * SFOLD);
    hj2.x = __float2bfloat16(njx * SFOLD);
    hj2.y = __float2bfloat16(njy * SFOLD);
    *reinterpret_cast<__hip_bfloat162*>(zb + (size_t)r * DIM + lane * 2) = hi2;
    *reinterpret_cast<__hip_bfloat162*>(zb + (size_t)(r + BATCH) * DIM + lane * 2) = hj2;

    // paired-diagonal dot in fp32 (unscaled)
    float d = nix * njx + niy * njy;
    #pragma unroll
    for (int m = 1; m < 64; m <<= 1) d += __shfl_xor(d, m, 64);

    __shared__ float red[4];
    if (lane == 0) red[w] = d;
    __syncthreads();
    if (threadIdx.x == 0)
        ps[blockIdx.x] = red[0] + red[1] + red[2] + red[3];
}

// ---------------------------------------------------------------------------
// Kernel 2: SYMMETRIC similarity, m97-style: 128x128 tile-pairs (rb<=cb),
// A/B panels staged via global_load_lds (wave-uniform LDS dest, PRE-SWIZZLED
// per-lane global source: blk' = blk ^ (row&7), an involution), then
// swizzled ds_read_b128 fragments (2-way bank aliasing = free) feeding
// 16x16x32 MFMA. 4 waves in a 2x2 grid, each 64x64 output, K=128 in 4 steps.
// Fused epilogue: exp2 (scale pre-folded), self-mask on diag blocks, row
// sums via register psum + atomicAdd, col sums (offdiag only, for the
// transposed tile) via LDS colacc + one atomic per col.
// Diag blocks stage only the A panel and read B-frags from it.
// ---------------------------------------------------------------------------
__global__ __launch_bounds__(256, 2) void k_sim(const __hip_bfloat16* __restrict__ zb,
                                                float* __restrict__ rowsum) {
    __shared__ unsigned short As[128 * 128];   // 32 KB  (A panel, K=128)
    __shared__ unsigned short Bs[128 * 128];   // 32 KB  (B panel)
    __shared__ float colacc[128];

    const int t = threadIdx.x;
    const int w = t >> 6;
    const int lane = t & 63;
    const int lo = lane & 15, hi = lane >> 4;
    const int wr = w >> 1, wc = w & 1;

    // block -> (rb, cb) upper-triangle pair
    const int pair = blockIdx.x;
    int rb = 0, accum = 0;
    while (accum + (NT - rb) <= pair) { accum += NT - rb; ++rb; }
    const int cb = rb + (pair - accum);
    const bool offdiag = (rb != cb);

    const int rbase = rb * 128;
    const int cbase = cb * 128;

    if (t < 128) colacc[t] = 0.0f;

    const char* zbB = reinterpret_cast<const char*>(zb);
    char* AsB = reinterpret_cast<char*>(As);
    char* BsB = reinterpret_cast<char*>(Bs);

    // ---- stage panels: 2048 chunks of 16B each per panel ----
    #pragma unroll
    for (int it = 0; it < 8; ++it) {
        int chunk = it * 256 + w * 64;          // wave-uniform
        int c = chunk + lane;
        int row = c >> 4, blk = c & 15;
        const char* srcA = zbB + (size_t)(rbase + row) * 256 + ((blk ^ (row & 7)) * 16);
        gload16(srcA, AsB + chunk * 16);
    }
    if (offdiag) {
        #pragma unroll
        for (int it = 0; it < 8; ++it) {
            int chunk = it * 256 + w * 64;
            int c = chunk + lane;
            int row = c >> 4, blk = c & 15;
            const char* srcB = zbB + (size_t)(cbase + row) * 256 + ((blk ^ (row & 7)) * 16);
            gload16(srcB, BsB + chunk * 16);
        }
    }
    __syncthreads();   // drains vmcnt (global_load_lds) before any ds_read

    const char* AsC = reinterpret_cast<const char*>(As);
    const char* BsC = offdiag ? reinterpret_cast<const char*>(Bs) : AsC;

    // ---- MFMA main: acc[i][j] over K=128 in 4 steps ----
    f32x4 acc[4][4];
    #pragma unroll
    for (int i = 0; i < 4; ++i)
        #pragma unroll
        for (int j = 0; j < 4; ++j) acc[i][j] = (f32x4){0.f, 0.f, 0.f, 0.f};

    #pragma unroll
    for (int ks = 0; ks < 4; ++ks) {
        bf16x8 a[4], b[4];
        #pragma unroll
        for (int i = 0; i < 4; ++i) {
            int r = wr * 64 + i * 16 + lo;
            int bk = (ks * 4 + hi) ^ (r & 7);
            a[i] = *reinterpret_cast<const bf16x8*>(AsC + r * 256 + bk * 16);
        }
        #pragma unroll
        for (int j = 0; j < 4; ++j) {
            int r = wc * 64 + j * 16 + lo;
            int bk = (ks * 4 + hi) ^ (r & 7);
            b[j] = *reinterpret_cast<const bf16x8*>(BsC + r * 256 + bk * 16);
        }
        #pragma unroll
        for (int i = 0; i < 4; ++i)
            #pragma unroll
            for (int j = 0; j < 4; ++j)
                acc[i][j] = __builtin_amdgcn_mfma_f32_16x16x32_bf16(
                    a[i], b[j], acc[i][j], 0, 0, 0);
    }

    // ---- fused epilogue ----
    // C/D layout (m89): out row = i*16 + hi*4 + p (A side), col = j*16 + lo.
    float psum[4][4];
    float cps[4] = {0.f, 0.f, 0.f, 0.f};
    #pragma unroll
    for (int i = 0; i < 4; ++i) {
        #pragma unroll
        for (int p = 0; p < 4; ++p) {
            float s = 0.0f;
            #pragma unroll
            for (int j = 0; j < 4; ++j) {
                float e = exp2f(acc[i][j][p]);
                if (!offdiag && wr == wc && j == i && lo == hi * 4 + p) e = 0.0f;
                s += e;
                cps[j] += e;
            }
            psum[i][p] = s;
        }
    }

    // row side: reduce over the 16 lo-lanes (distinct cols), atomic per row.
    #pragma unroll
    for (int i = 0; i < 4; ++i) {
        #pragma unroll
        for (int p = 0; p < 4; ++p) {
            float s = psum[i][p];
            s += __shfl_xor(s, 1, 64);
            s += __shfl_xor(s, 2, 64);
            s += __shfl_xor(s, 4, 64);
            s += __shfl_xor(s, 8, 64);
            if (lo == 0)
                atomicAdd(&rowsum[rbase + wr * 64 + i * 16 + hi * 4 + p], s);
        }
    }

    // col side (transposed tile coverage), offdiag only.
    if (offdiag) {
        #pragma unroll
        for (int j = 0; j < 4; ++j) {
            float v = cps[j];
            v += __shfl_xor(v, 16, 64);
            v += __shfl_xor(v, 32, 64);
            if (hi == 0)
                atomicAdd(&colacc[wc * 64 + j * 16 + lo], v);
        }
        __syncthreads();
        if (t < 128) atomicAdd(&rowsum[cbase + t], colacc[t]);
    }
}

// ---------------------------------------------------------------------------
// Kernel 3: loss = (sum_r log(rowsum[r]) - 2*INV_TEMP*possum) / TWO_B
// ---------------------------------------------------------------------------
__global__ __launch_bounds__(1024) void k_final(const float* __restrict__ rowsum,
                                                const float* __restrict__ ps,
                                                float* __restrict__ out) {
    __shared__ float redl[1024];
    __shared__ float redp[1024];
    const int t = threadIdx.x;

    float s = 0.0f;
    #pragma unroll
    for (int q = 0; q < TWO_B / 1024; ++q) s += logf(rowsum[t + q * 1024]);
    float p = ps[t];

    redl[t] = s;
    redp[t] = p;
    __syncthreads();
    #pragma unroll
    for (int off = 512; off > 0; off >>= 1) {
        if (t < off) {
            redl[t] += redl[t + off];
            redp[t] += redp[t + off];
        }
        __syncthreads();
    }
    if (t == 0)
        out[0] = (redl[0] - 2.0f * INV_TEMP * redp[0]) / (float)TWO_B;
}

// ---------------------------------------------------------------------------
extern "C" void kernel_launch(void* const* d_in, const int* in_sizes, int n_in,
                              void* d_out, int out_size, void* d_ws, size_t ws_size,
                              hipStream_t stream) {
    const float* zi = (const float*)d_in[0];
    const float* zj = (const float*)d_in[1];
    float* out = (float*)d_out;

    char* ws = (char*)d_ws;
    __hip_bfloat16* zb = (__hip_bfloat16*)ws;
    float* rowsum = (float*)(ws + RS_OFFSET);
    float* ps = (float*)(ws + PS_OFFSET);

    k_normalize<<<BATCH / 4, 256, 0, stream>>>(zi, zj, zb, ps, rowsum);
    k_sim<<<NPAIRS, 256, 0, stream>>>(zb, rowsum);
    k_final<<<1, 1024, 0, stream>>>(rowsum, ps, out);
}